// Round 4
// baseline (225.097 us; speedup 1.0000x reference)
//
#include <hip/hip_runtime.h>

// Problem constants (reference: T=4096, N_ENVS=2048, fp32)
#define TT    4096
#define NENV  2048
#define N4    (NENV / 4)          // float4 columns = 512
#define L     8                   // timesteps per chunk
#define NCH   (TT / L)            // 512 chunks
#define TPCH  (NENV / 4)          // 512 threads per chunk (4 cols each)
#define NCGRP (TPCH / 256)        // 2 blocks per chunk
#define NBLK  (NCH * NCGRP)       // 1024 blocks

#define GAMMA 0.99f
#define GL    (0.99f * 0.95f)

// Per-component GAE chunk-affine step: B = di + c*B ; A = c*A
#define STEP_AB(r_, v_, nv_, dn_, A_, B_)                    \
    {                                                        \
        const float nd = (dn_) ? 0.0f : 1.0f;                \
        const float di = (r_) + GAMMA * (nv_) * nd - (v_);   \
        const float c  = GL * nd;                            \
        (B_) = di + c * (B_);                                \
        (A_) = c * (A_);                                     \
    }

// Per-component replay step: g = di + GL*nd*g ; adv = g ; ret = g + v
#define STEP_OUT(r_, v_, nv_, dn_, g_, adv_, ret_)           \
    {                                                        \
        const float nd = (dn_) ? 0.0f : 1.0f;                \
        const float di = (r_) + GAMMA * (nv_) * nd - (v_);   \
        (g_) = di + GL * nd * (g_);                          \
        (adv_) = (g_);                                       \
        (ret_) = (g_) + (v_);                                \
    }

// ---- k1: per-chunk affine (A,B) for every column, streaming inputs once ----
__global__ __launch_bounds__(256) void gae_k1(
    const float4* __restrict__ r4,
    const float4* __restrict__ v4,
    const float4* __restrict__ nv4,
    const int4*   __restrict__ dn4,
    float4* __restrict__ wsA,     // [NCH][N4]
    float4* __restrict__ wsB)     // [NCH][N4]
{
    const int chunk = blockIdx.x / NCGRP;                      // 0..511
    const int c4    = (blockIdx.x % NCGRP) * 256 + threadIdx.x; // 0..511
    const int t0    = chunk * L;

    float Ax = 1.0f, Ay = 1.0f, Az = 1.0f, Aw = 1.0f;
    float Bx = 0.0f, By = 0.0f, Bz = 0.0f, Bw = 0.0f;

#pragma unroll
    for (int i = L - 1; i >= 0; --i) {
        const int idx = (t0 + i) * N4 + c4;                    // coalesced 16B/lane
        const float4 r  = r4[idx];
        const float4 v  = v4[idx];
        const float4 nv = nv4[idx];
        const int4   dn = dn4[idx];
        STEP_AB(r.x, v.x, nv.x, dn.x, Ax, Bx);
        STEP_AB(r.y, v.y, nv.y, dn.y, Ay, By);
        STEP_AB(r.z, v.z, nv.z, dn.z, Az, Bz);
        STEP_AB(r.w, v.w, nv.w, dn.w, Aw, Bw);
    }
    wsA[chunk * N4 + c4] = make_float4(Ax, Ay, Az, Aw);
    wsB[chunk * N4 + c4] = make_float4(Bx, By, Bz, Bw);
}

// ---- k2: serial suffix scan over chunks, one thread per column ----
__global__ __launch_bounds__(256) void gae_k2(
    const float* __restrict__ wsA,
    const float* __restrict__ wsB,
    float* __restrict__ gIn)      // [NCH][NENV]: incoming g for each chunk
{
    const int col = blockIdx.x * 256 + threadIdx.x;   // 2048 threads
    float g = 0.0f;
#pragma unroll 8
    for (int j = NCH - 1; j >= 0; --j) {
        gIn[j * NENV + col] = g;
        g = wsB[j * NENV + col] + wsA[j * NENV + col] * g;
    }
}

// ---- k3: replay recurrence per chunk (inputs L3-warm), write adv & returns ----
__global__ __launch_bounds__(256) void gae_k3(
    const float4* __restrict__ r4,
    const float4* __restrict__ v4,
    const float4* __restrict__ nv4,
    const int4*   __restrict__ dn4,
    const float4* __restrict__ gIn4,   // [NCH][N4]
    float4* __restrict__ adv4,
    float4* __restrict__ ret4)
{
    const int chunk = blockIdx.x / NCGRP;
    const int c4    = (blockIdx.x % NCGRP) * 256 + threadIdx.x;
    const int t0    = chunk * L;

    const float4 g0 = gIn4[chunk * N4 + c4];
    float gx = g0.x, gy = g0.y, gz = g0.z, gw = g0.w;

#pragma unroll
    for (int i = L - 1; i >= 0; --i) {
        const int idx = (t0 + i) * N4 + c4;
        const float4 r  = r4[idx];
        const float4 v  = v4[idx];
        const float4 nv = nv4[idx];
        const int4   dn = dn4[idx];
        float4 a, t;
        STEP_OUT(r.x, v.x, nv.x, dn.x, gx, a.x, t.x);
        STEP_OUT(r.y, v.y, nv.y, dn.y, gy, a.y, t.y);
        STEP_OUT(r.z, v.z, nv.z, dn.z, gz, a.z, t.z);
        STEP_OUT(r.w, v.w, nv.w, dn.w, gw, a.w, t.w);
        adv4[idx] = a;
        ret4[idx] = t;
    }
}

extern "C" void kernel_launch(void* const* d_in, const int* in_sizes, int n_in,
                              void* d_out, int out_size, void* d_ws, size_t ws_size,
                              hipStream_t stream) {
    const float4* r4  = (const float4*)d_in[0];
    const float4* v4  = (const float4*)d_in[1];
    const float4* nv4 = (const float4*)d_in[2];
    const int4*   dn4 = (const int4*)d_in[3];

    float4* adv4 = (float4*)d_out;
    float4* ret4 = adv4 + (size_t)TT * N4;

    float4* wsA = (float4*)d_ws;                    // NCH*N4 float4 = 4 MiB
    float4* wsB = wsA + (size_t)NCH * N4;           // 4 MiB
    float*  gIn = (float*)(wsB + (size_t)NCH * N4); // NCH*NENV floats = 4 MiB

    gae_k1<<<NBLK, 256, 0, stream>>>(r4, v4, nv4, dn4, wsA, wsB);
    gae_k2<<<NENV / 256, 256, 0, stream>>>((const float*)wsA, (const float*)wsB, gIn);
    gae_k3<<<NBLK, 256, 0, stream>>>(r4, v4, nv4, dn4, (const float4*)gIn,
                                     adv4, ret4);
}